// Round 1
// baseline (286.529 us; speedup 1.0000x reference)
//
#include <hip/hip_runtime.h>
#include <math.h>

#define B_  8
#define T_  2048
#define D_  1024
#define E_  8
#define FF_ 4096
#define N_  64            // B*E rows through the FFN
#define BT_ (B_*T_)

// ---------------------------------------------------------------------------
// K1: logits[bt][e] = X[bt]·Wg[:,e] + bg[e]; also accumulate per-(b,e)
//     sum over T of exp(logit) (dispatch-softmax denominator) via block
//     partial reduction + one atomicAdd per (block, e).
// ---------------------------------------------------------------------------
__global__ __launch_bounds__(256) void k_logits(
    const float* __restrict__ X, const float* __restrict__ Wg,
    const float* __restrict__ bg, float* __restrict__ logits,
    float* __restrict__ sumexp)
{
    __shared__ float wgT[E_ * D_];     // Wg transposed: [e][d], 32 KB
    __shared__ float xt[32 * 132];     // 32 tokens x 128 d (padded), 16.9 KB
    __shared__ float red[256];

    const int tid = threadIdx.x;

    // stage Wg transposed (coalesced global read, minor LDS write conflicts ok)
    #pragma unroll
    for (int r = 0; r < 32; ++r) {
        int idx = r * 256 + tid;                  // idx = d*8 + e
        wgT[(idx & 7) * D_ + (idx >> 3)] = Wg[idx];
    }

    const int bt0 = blockIdx.x * 32;              // 32 tokens per block
    const int tok = tid >> 3;                     // 0..31
    const int e   = tid & 7;                      // 0..7
    float acc = 0.f;

    for (int dt = 0; dt < 8; ++dt) {
        __syncthreads();                          // covers wgT on first iter
        #pragma unroll
        for (int r = 0; r < 4; ++r) {
            int idx4 = r * 256 + tid;
            int row = idx4 >> 5, c4 = idx4 & 31;
            const float4 v = *(const float4*)&X[(size_t)(bt0 + row) * D_ + dt * 128 + c4 * 4];
            *(float4*)&xt[row * 132 + c4 * 4] = v;
        }
        __syncthreads();
        const float4* xp = (const float4*)&xt[tok * 132];
        const float4* wp = (const float4*)&wgT[e * D_ + dt * 128];
        #pragma unroll
        for (int j = 0; j < 32; ++j) {
            const float4 xv = xp[j];
            const float4 wv = wp[j];
            acc += xv.x * wv.x + xv.y * wv.y + xv.z * wv.z + xv.w * wv.w;
        }
    }

    const float lg = acc + bg[e];
    logits[(size_t)(bt0 + tok) * E_ + e] = lg;

    // dispatch-softmax denominator partials (sum over the 32 tokens, per e)
    red[tid] = expf(lg);
    __syncthreads();
    for (int s = 128; s >= 8; s >>= 1) {
        if (tid < s) red[tid] += red[tid + s];
        __syncthreads();
    }
    if (tid < 8) {
        atomicAdd(&sumexp[(bt0 >> 11) * E_ + tid], red[tid]);
    }
}

// ---------------------------------------------------------------------------
// K2: slots partials. part[ts][(b*8+e)*1024 + d] = sum over 64-token slice of
//     dispatch_w[b,t,e] * X[b,t,d]. Grid (ts=32, b=8); 256 threads = 1024 d
//     via float4 per thread.
// ---------------------------------------------------------------------------
__global__ __launch_bounds__(256) void k_slots_part(
    const float* __restrict__ X, const float* __restrict__ logits,
    const float* __restrict__ sumexp, float* __restrict__ part)
{
    __shared__ float wlds[64 * 8];
    __shared__ float inv[8];

    const int tid = threadIdx.x;
    const int ts = blockIdx.x, b = blockIdx.y;
    const int t0 = ts * 64;

    if (tid < 8) inv[tid] = 1.f / sumexp[b * E_ + tid];
    __syncthreads();
    #pragma unroll
    for (int r = 0; r < 2; ++r) {
        int idx = r * 256 + tid;                  // idx = t*8 + e over 64 tokens
        wlds[idx] = expf(logits[(size_t)b * T_ * E_ + (size_t)t0 * E_ + idx]) * inv[idx & 7];
    }
    __syncthreads();

    float4 acc[8];
    #pragma unroll
    for (int e = 0; e < 8; ++e) { acc[e].x = acc[e].y = acc[e].z = acc[e].w = 0.f; }

    const float* xb = &X[((size_t)b * T_ + t0) * D_ + tid * 4];
    for (int t = 0; t < 64; ++t) {
        const float4 x4 = *(const float4*)&xb[(size_t)t * D_];
        const float4 wA = *(const float4*)&wlds[t * 8];
        const float4 wB = *(const float4*)&wlds[t * 8 + 4];
        const float w[8] = {wA.x, wA.y, wA.z, wA.w, wB.x, wB.y, wB.z, wB.w};
        #pragma unroll
        for (int e = 0; e < 8; ++e) {
            acc[e].x += x4.x * w[e];
            acc[e].y += x4.y * w[e];
            acc[e].z += x4.z * w[e];
            acc[e].w += x4.w * w[e];
        }
    }
    #pragma unroll
    for (int e = 0; e < 8; ++e) {
        *(float4*)&part[(size_t)ts * (N_ * D_) + (size_t)(b * E_ + e) * D_ + tid * 4] = acc[e];
    }
}

// K3: reduce 32 slot partials -> slots[64][1024]
__global__ __launch_bounds__(256) void k_reduce_slots(
    const float* __restrict__ part, float* __restrict__ slots)
{
    const int i = blockIdx.x * 256 + threadIdx.x;     // 65536
    float s = 0.f;
    #pragma unroll
    for (int p = 0; p < 32; ++p) s += part[(size_t)p * (N_ * D_) + i];
    slots[i] = s;
}

// ---------------------------------------------------------------------------
// K4/K6: generic k-split GEMM partial: part[kc][n][f] = sum_{k in tile}
//        A[n][k] * W[k][f].  A is 64 x K. Thread owns 2 f-columns x 64 rows.
//        grid.x = F/512 f-chunks, grid.y = K/32 k-chunks (ktile = 32).
// ---------------------------------------------------------------------------
__global__ __launch_bounds__(256) void k_gemm_part(
    const float* __restrict__ A, const float* __restrict__ W,
    float* __restrict__ part, int K, int F)
{
    __shared__ float sT[32 * 68];                 // [kk][n], pad 68 vs 64

    const int tid = threadIdx.x;
    const int f0 = blockIdx.x * 512 + tid;
    const int k0 = blockIdx.y * 32;

    #pragma unroll
    for (int r = 0; r < 8; ++r) {                 // 2048 elements
        int idx = r * 256 + tid;
        int n = idx >> 5, kk = idx & 31;
        sT[kk * 68 + n] = A[(size_t)n * K + k0 + kk];
    }
    __syncthreads();

    float acc0[64], acc1[64];
    #pragma unroll
    for (int n = 0; n < 64; ++n) { acc0[n] = 0.f; acc1[n] = 0.f; }

    #pragma unroll 4
    for (int kk = 0; kk < 32; ++kk) {
        const float w0 = W[(size_t)(k0 + kk) * F + f0];
        const float w1 = W[(size_t)(k0 + kk) * F + f0 + 256];
        const float4* sp = (const float4*)&sT[kk * 68];   // broadcast reads
        #pragma unroll
        for (int j = 0; j < 16; ++j) {
            const float4 s = sp[j];
            acc0[4*j+0] += s.x * w0; acc0[4*j+1] += s.y * w0;
            acc0[4*j+2] += s.z * w0; acc0[4*j+3] += s.w * w0;
            acc1[4*j+0] += s.x * w1; acc1[4*j+1] += s.y * w1;
            acc1[4*j+2] += s.z * w1; acc1[4*j+3] += s.w * w1;
        }
    }

    const size_t base = (size_t)blockIdx.y * N_ * F;
    #pragma unroll
    for (int n = 0; n < 64; ++n) {
        part[base + (size_t)n * F + f0]       = acc0[n];
        part[base + (size_t)n * F + f0 + 256] = acc1[n];
    }
}

// K5: reduce 32 GEMM1 partials + b1, SiLU -> h[64][4096]
__global__ __launch_bounds__(256) void k_reduce_silu(
    const float* __restrict__ part, const float* __restrict__ b1,
    float* __restrict__ h)
{
    const int i = blockIdx.x * 256 + threadIdx.x;     // 262144
    float s = 0.f;
    #pragma unroll
    for (int p = 0; p < 32; ++p) s += part[(size_t)p * (N_ * FF_) + i];
    s += b1[i & (FF_ - 1)];
    h[i] = s / (1.f + expf(-s));                      // silu
}

// K7: reduce 128 GEMM2 partials + b2 -> y[64][1024]
__global__ __launch_bounds__(256) void k_reduce_bias(
    const float* __restrict__ part, const float* __restrict__ b2,
    float* __restrict__ y)
{
    const int i = blockIdx.x * 256 + threadIdx.x;     // 65536
    float s = 0.f;
    #pragma unroll
    for (int p = 0; p < 128; ++p) s += part[(size_t)p * (N_ * D_) + i];
    y[i] = s + b2[i & (D_ - 1)];
}

// ---------------------------------------------------------------------------
// K8: out[b][t][d] = sum_e softmax_e(logits[b,t,:])[e] * y[b*8+e][d]
//     grid (dc=4, tc=32, b=8); thread owns one d, y values in registers.
// ---------------------------------------------------------------------------
__global__ __launch_bounds__(256) void k_combine(
    const float* __restrict__ logits, const float* __restrict__ y,
    float* __restrict__ out)
{
    __shared__ float wlds[64 * 8];
    const int tid = threadIdx.x;
    const int dc = blockIdx.x, tc = blockIdx.y, b = blockIdx.z;
    const int t0 = tc * 64;

    if (tid < 64) {
        const float* lp = &logits[((size_t)b * T_ + t0 + tid) * E_];
        float ex[8]; float s = 0.f;
        #pragma unroll
        for (int i = 0; i < 8; ++i) { ex[i] = expf(lp[i]); s += ex[i]; }
        const float invs = 1.f / s;
        #pragma unroll
        for (int i = 0; i < 8; ++i) wlds[tid * 8 + i] = ex[i] * invs;
    }
    __syncthreads();

    const int d = dc * 256 + tid;
    float yv[8];
    #pragma unroll
    for (int e = 0; e < 8; ++e) yv[e] = y[(size_t)(b * E_ + e) * D_ + d];

    for (int t = 0; t < 64; ++t) {
        const float4 wA = *(const float4*)&wlds[t * 8];
        const float4 wB = *(const float4*)&wlds[t * 8 + 4];
        const float acc = wA.x * yv[0] + wA.y * yv[1] + wA.z * yv[2] + wA.w * yv[3]
                        + wB.x * yv[4] + wB.y * yv[5] + wB.z * yv[6] + wB.w * yv[7];
        out[((size_t)b * T_ + t0 + t) * D_ + d] = acc;
    }
}

// ---------------------------------------------------------------------------
extern "C" void kernel_launch(void* const* d_in, const int* in_sizes, int n_in,
                              void* d_out, int out_size, void* d_ws, size_t ws_size,
                              hipStream_t stream)
{
    const float* X  = (const float*)d_in[0];
    const float* Wg = (const float*)d_in[1];
    const float* bg = (const float*)d_in[2];
    const float* W1 = (const float*)d_in[3];
    const float* b1 = (const float*)d_in[4];
    const float* W2 = (const float*)d_in[5];
    const float* b2 = (const float*)d_in[6];
    float* out = (float*)d_out;

    // ws layout (fp32), ~2.1 MB total
    float* wsf    = (float*)d_ws;
    float* logits = wsf;                        // 131072
    float* sumexp = logits + BT_ * E_;          // 64
    float* slots  = sumexp + 64;                // 65536
    float* h      = slots + N_ * D_;            // 262144
    float* y      = h + N_ * FF_;               // 65536

    // Large partial buffers live in d_out (64 MB), which is fully
    // overwritten by k_combine at the end. Max partial usage = 32 MB.
    float* part = out;

    hipMemsetAsync(sumexp, 0, 64 * sizeof(float), stream);

    hipLaunchKernelGGL(k_logits,       dim3(BT_ / 32), dim3(256), 0, stream,
                       X, Wg, bg, logits, sumexp);
    hipLaunchKernelGGL(k_slots_part,   dim3(32, 8),    dim3(256), 0, stream,
                       X, logits, sumexp, part);
    hipLaunchKernelGGL(k_reduce_slots, dim3(256),      dim3(256), 0, stream,
                       part, slots);
    hipLaunchKernelGGL(k_gemm_part,    dim3(FF_ / 512, 1024 / 32), dim3(256), 0, stream,
                       slots, W1, part, 1024, FF_);
    hipLaunchKernelGGL(k_reduce_silu,  dim3(N_ * FF_ / 256), dim3(256), 0, stream,
                       part, b1, h);
    hipLaunchKernelGGL(k_gemm_part,    dim3(D_ / 512, FF_ / 32), dim3(256), 0, stream,
                       h, W2, part, FF_, D_);
    hipLaunchKernelGGL(k_reduce_bias,  dim3(N_ * D_ / 256), dim3(256), 0, stream,
                       part, b2, y);
    hipLaunchKernelGGL(k_combine,      dim3(4, 32, 8), dim3(256), 0, stream,
                       logits, y, out);
}

// Round 2
// 271.835 us; speedup vs baseline: 1.0541x; 1.0541x over previous
//
#include <hip/hip_runtime.h>
#include <math.h>

#define B_  8
#define T_  2048
#define D_  1024
#define E_  8
#define FF_ 4096
#define N_  64            // B*E rows through the FFN
#define BT_ (B_*T_)
#define WGS 1028          // padded wgT stride: e*1028 % 32 = 4e -> disjoint bank quads

// ---------------------------------------------------------------------------
// K1: logits[bt][e] = X[bt]·Wg[:,e] + bg[e]; also accumulate per-(b,e)
//     sum over T of exp(logit) (dispatch-softmax denominator) via block
//     partial reduction + one atomicAdd per (block, e).
// ---------------------------------------------------------------------------
__global__ __launch_bounds__(256) void k_logits(
    const float* __restrict__ X, const float* __restrict__ Wg,
    const float* __restrict__ bg, float* __restrict__ logits,
    float* __restrict__ sumexp)
{
    __shared__ float wgT[E_ * WGS];    // Wg transposed: [e][d], padded, 32.9 KB
    __shared__ float xt[32 * 132];     // 32 tokens x 128 d (padded), 16.9 KB
    __shared__ float red[256];

    const int tid = threadIdx.x;

    // stage Wg transposed (coalesced global read; write banks (4b+a)%32 -> 2-way max)
    #pragma unroll
    for (int r = 0; r < 32; ++r) {
        int idx = r * 256 + tid;                  // idx = d*8 + e
        wgT[(idx & 7) * WGS + (idx >> 3)] = Wg[idx];
    }

    const int bt0 = blockIdx.x * 32;              // 32 tokens per block
    const int tok = tid >> 3;                     // 0..31
    const int e   = tid & 7;                      // 0..7
    float acc = 0.f;

    for (int dt = 0; dt < 8; ++dt) {
        __syncthreads();                          // covers wgT on first iter
        #pragma unroll
        for (int r = 0; r < 4; ++r) {
            int idx4 = r * 256 + tid;
            int row = idx4 >> 5, c4 = idx4 & 31;
            const float4 v = *(const float4*)&X[(size_t)(bt0 + row) * D_ + dt * 128 + c4 * 4];
            *(float4*)&xt[row * 132 + c4 * 4] = v;
        }
        __syncthreads();
        const float4* xp = (const float4*)&xt[tok * 132];
        const float4* wp = (const float4*)&wgT[e * WGS + dt * 128];
        #pragma unroll
        for (int j = 0; j < 32; ++j) {
            const float4 xv = xp[j];
            const float4 wv = wp[j];
            acc += xv.x * wv.x + xv.y * wv.y + xv.z * wv.z + xv.w * wv.w;
        }
    }

    const float lg = acc + bg[e];
    logits[(size_t)(bt0 + tok) * E_ + e] = lg;

    // dispatch-softmax denominator partials (sum over the 32 tokens, per e)
    red[tid] = expf(lg);
    __syncthreads();
    for (int s = 128; s >= 8; s >>= 1) {
        if (tid < s) red[tid] += red[tid + s];
        __syncthreads();
    }
    if (tid < 8) {
        atomicAdd(&sumexp[(bt0 >> 11) * E_ + tid], red[tid]);
    }
}

// ---------------------------------------------------------------------------
// K2: slots partials. part[ts][(b*8+e)*1024 + d] = sum over 64-token slice of
//     dispatch_w[b,t,e] * X[b,t,d]. Grid (ts=32, b=8); 256 threads = 1024 d
//     via float4 per thread.
// ---------------------------------------------------------------------------
__global__ __launch_bounds__(256) void k_slots_part(
    const float* __restrict__ X, const float* __restrict__ logits,
    const float* __restrict__ sumexp, float* __restrict__ part)
{
    __shared__ float wlds[64 * 8];
    __shared__ float inv[8];

    const int tid = threadIdx.x;
    const int ts = blockIdx.x, b = blockIdx.y;
    const int t0 = ts * 64;

    if (tid < 8) inv[tid] = 1.f / sumexp[b * E_ + tid];
    __syncthreads();
    #pragma unroll
    for (int r = 0; r < 2; ++r) {
        int idx = r * 256 + tid;                  // idx = t*8 + e over 64 tokens
        wlds[idx] = expf(logits[(size_t)b * T_ * E_ + (size_t)t0 * E_ + idx]) * inv[idx & 7];
    }
    __syncthreads();

    float4 acc[8];
    #pragma unroll
    for (int e = 0; e < 8; ++e) { acc[e].x = acc[e].y = acc[e].z = acc[e].w = 0.f; }

    const float* xb = &X[((size_t)b * T_ + t0) * D_ + tid * 4];
    #pragma unroll 4
    for (int t = 0; t < 64; ++t) {
        const float4 x4 = *(const float4*)&xb[(size_t)t * D_];
        const float4 wA = *(const float4*)&wlds[t * 8];
        const float4 wB = *(const float4*)&wlds[t * 8 + 4];
        const float w[8] = {wA.x, wA.y, wA.z, wA.w, wB.x, wB.y, wB.z, wB.w};
        #pragma unroll
        for (int e = 0; e < 8; ++e) {
            acc[e].x += x4.x * w[e];
            acc[e].y += x4.y * w[e];
            acc[e].z += x4.z * w[e];
            acc[e].w += x4.w * w[e];
        }
    }
    #pragma unroll
    for (int e = 0; e < 8; ++e) {
        *(float4*)&part[(size_t)ts * (N_ * D_) + (size_t)(b * E_ + e) * D_ + tid * 4] = acc[e];
    }
}

// K3: reduce 32 slot partials -> slots[64][1024]
__global__ __launch_bounds__(256) void k_reduce_slots(
    const float* __restrict__ part, float* __restrict__ slots)
{
    const int i = blockIdx.x * 256 + threadIdx.x;     // 65536
    float s = 0.f;
    #pragma unroll
    for (int p = 0; p < 32; ++p) s += part[(size_t)p * (N_ * D_) + i];
    slots[i] = s;
}

// ---------------------------------------------------------------------------
// K4/K6: generic k-split GEMM partial: part[kc][n][f] = sum_{k in tile}
//        A[n][k] * W[k][f].  A is 64 x K. Thread owns 2 f-columns x 64 rows.
//        grid.x = F/512 f-chunks, grid.y = K/32 k-chunks (ktile = 32).
// ---------------------------------------------------------------------------
__global__ __launch_bounds__(256) void k_gemm_part(
    const float* __restrict__ A, const float* __restrict__ W,
    float* __restrict__ part, int K, int F)
{
    __shared__ float sT[32 * 68];                 // [kk][n], pad 68 vs 64

    const int tid = threadIdx.x;
    const int f0 = blockIdx.x * 512 + tid;
    const int k0 = blockIdx.y * 32;

    #pragma unroll
    for (int r = 0; r < 8; ++r) {                 // 2048 elements
        int idx = r * 256 + tid;
        int n = idx >> 5, kk = idx & 31;
        sT[kk * 68 + n] = A[(size_t)n * K + k0 + kk];
    }
    __syncthreads();

    float acc0[64], acc1[64];
    #pragma unroll
    for (int n = 0; n < 64; ++n) { acc0[n] = 0.f; acc1[n] = 0.f; }

    #pragma unroll 4
    for (int kk = 0; kk < 32; ++kk) {
        const float w0 = W[(size_t)(k0 + kk) * F + f0];
        const float w1 = W[(size_t)(k0 + kk) * F + f0 + 256];
        const float4* sp = (const float4*)&sT[kk * 68];   // broadcast reads
        #pragma unroll
        for (int j = 0; j < 16; ++j) {
            const float4 s = sp[j];
            acc0[4*j+0] += s.x * w0; acc0[4*j+1] += s.y * w0;
            acc0[4*j+2] += s.z * w0; acc0[4*j+3] += s.w * w0;
            acc1[4*j+0] += s.x * w1; acc1[4*j+1] += s.y * w1;
            acc1[4*j+2] += s.z * w1; acc1[4*j+3] += s.w * w1;
        }
    }

    const size_t base = (size_t)blockIdx.y * N_ * F;
    #pragma unroll
    for (int n = 0; n < 64; ++n) {
        part[base + (size_t)n * F + f0]       = acc0[n];
        part[base + (size_t)n * F + f0 + 256] = acc1[n];
    }
}

// K5: reduce 32 GEMM1 partials + b1, SiLU -> h[64][4096]
__global__ __launch_bounds__(256) void k_reduce_silu(
    const float* __restrict__ part, const float* __restrict__ b1,
    float* __restrict__ h)
{
    const int i = blockIdx.x * 256 + threadIdx.x;     // 262144
    float s = 0.f;
    #pragma unroll
    for (int p = 0; p < 32; ++p) s += part[(size_t)p * (N_ * FF_) + i];
    s += b1[i & (FF_ - 1)];
    h[i] = s / (1.f + expf(-s));                      // silu
}

// K7: reduce 128 GEMM2 partials + b2 -> y[64][1024]
__global__ __launch_bounds__(256) void k_reduce_bias(
    const float* __restrict__ part, const float* __restrict__ b2,
    float* __restrict__ y)
{
    const int i = blockIdx.x * 256 + threadIdx.x;     // 65536
    float s = 0.f;
    #pragma unroll
    for (int p = 0; p < 128; ++p) s += part[(size_t)p * (N_ * D_) + i];
    y[i] = s + b2[i & (D_ - 1)];
}

// ---------------------------------------------------------------------------
// K8: out[b][t][d] = sum_e softmax_e(logits[b,t,:])[e] * y[b*8+e][d]
//     grid (dc=4, tc=32, b=8); thread owns one d, y values in registers.
// ---------------------------------------------------------------------------
__global__ __launch_bounds__(256) void k_combine(
    const float* __restrict__ logits, const float* __restrict__ y,
    float* __restrict__ out)
{
    __shared__ float wlds[64 * 8];
    const int tid = threadIdx.x;
    const int dc = blockIdx.x, tc = blockIdx.y, b = blockIdx.z;
    const int t0 = tc * 64;

    if (tid < 64) {
        const float* lp = &logits[((size_t)b * T_ + t0 + tid) * E_];
        float ex[8]; float s = 0.f;
        #pragma unroll
        for (int i = 0; i < 8; ++i) { ex[i] = expf(lp[i]); s += ex[i]; }
        const float invs = 1.f / s;
        #pragma unroll
        for (int i = 0; i < 8; ++i) wlds[tid * 8 + i] = ex[i] * invs;
    }
    __syncthreads();

    const int d = dc * 256 + tid;
    float yv[8];
    #pragma unroll
    for (int e = 0; e < 8; ++e) yv[e] = y[(size_t)(b * E_ + e) * D_ + d];

    for (int t = 0; t < 64; ++t) {
        const float4 wA = *(const float4*)&wlds[t * 8];
        const float4 wB = *(const float4*)&wlds[t * 8 + 4];
        const float acc = wA.x * yv[0] + wA.y * yv[1] + wA.z * yv[2] + wA.w * yv[3]
                        + wB.x * yv[4] + wB.y * yv[5] + wB.z * yv[6] + wB.w * yv[7];
        out[((size_t)b * T_ + t0 + t) * D_ + d] = acc;
    }
}

// ---------------------------------------------------------------------------
extern "C" void kernel_launch(void* const* d_in, const int* in_sizes, int n_in,
                              void* d_out, int out_size, void* d_ws, size_t ws_size,
                              hipStream_t stream)
{
    const float* X  = (const float*)d_in[0];
    const float* Wg = (const float*)d_in[1];
    const float* bg = (const float*)d_in[2];
    const float* W1 = (const float*)d_in[3];
    const float* b1 = (const float*)d_in[4];
    const float* W2 = (const float*)d_in[5];
    const float* b2 = (const float*)d_in[6];
    float* out = (float*)d_out;

    // ws layout (fp32), ~2.1 MB total
    float* wsf    = (float*)d_ws;
    float* logits = wsf;                        // 131072
    float* sumexp = logits + BT_ * E_;          // 64
    float* slots  = sumexp + 64;                // 65536
    float* h      = slots + N_ * D_;            // 262144
    float* y      = h + N_ * FF_;               // 65536

    // Large partial buffers live in d_out (64 MB), which is fully
    // overwritten by k_combine at the end. Max partial usage = 32 MB.
    float* part = out;

    hipMemsetAsync(sumexp, 0, 64 * sizeof(float), stream);

    hipLaunchKernelGGL(k_logits,       dim3(BT_ / 32), dim3(256), 0, stream,
                       X, Wg, bg, logits, sumexp);
    hipLaunchKernelGGL(k_slots_part,   dim3(32, 8),    dim3(256), 0, stream,
                       X, logits, sumexp, part);
    hipLaunchKernelGGL(k_reduce_slots, dim3(256),      dim3(256), 0, stream,
                       part, slots);
    hipLaunchKernelGGL(k_gemm_part,    dim3(FF_ / 512, 1024 / 32), dim3(256), 0, stream,
                       slots, W1, part, 1024, FF_);
    hipLaunchKernelGGL(k_reduce_silu,  dim3(N_ * FF_ / 256), dim3(256), 0, stream,
                       part, b1, h);
    hipLaunchKernelGGL(k_gemm_part,    dim3(D_ / 512, FF_ / 32), dim3(256), 0, stream,
                       h, W2, part, FF_, D_);
    hipLaunchKernelGGL(k_reduce_bias,  dim3(N_ * D_ / 256), dim3(256), 0, stream,
                       part, b2, y);
    hipLaunchKernelGGL(k_combine,      dim3(4, 32, 8), dim3(256), 0, stream,
                       logits, y, out);
}